// Round 11
// baseline (383.840 us; speedup 1.0000x reference)
//
#include <hip/hip_runtime.h>
#include <hip/hip_bf16.h>

typedef unsigned short u16;
typedef short s16x8 __attribute__((ext_vector_type(8)));
typedef float f32x4 __attribute__((ext_vector_type(4)));

#define MFMA_BF16(a, b, c) __builtin_amdgcn_mfma_f32_16x16x32_bf16((a), (b), (c), 0, 0, 0)

static constexpr int D_IN   = 64;
static constexpr int H_DIM  = 512;
static constexpr int M_TILE = 64;
static constexpr int AST    = 520;  // LDS row stride (bf16)
static constexpr int XST    = 72;   // LDS row stride for x tile (lives inside buf)

__device__ __forceinline__ u16 f2bf(float f) {
  unsigned u = __builtin_bit_cast(unsigned, f);
  u += 0x7fffu + ((u >> 16) & 1u);   // RNE
  return (u16)(u >> 16);
}
__device__ __forceinline__ float bfb2f(unsigned bits16) {
  return __builtin_bit_cast(float, bits16 << 16);
}
__device__ __forceinline__ float fast_tanh(float x) {
  float e = __expf(2.0f * x);
  return 1.0f - 2.0f * __builtin_amdgcn_rcpf(e + 1.0f);
}

// ---- prep: fp32 weights -> bf16, packed in MFMA-B-fragment order ----
// For each (ntg = 16-col tile, kc = 32-wide K chunk): 512 elems stored as
// lane*8 contiguous, lane=(q*16+ln), elem j -> B[k=kc*32+q*8+j][n=ntg*16+ln].
// ws layout (bf16): p0f[64x512] p0b[512x64] p1f p1b p2f p2b  (~2.2MB)
__global__ void prep_weights(const float* __restrict__ W0,
                             const float* __restrict__ W1,
                             const float* __restrict__ W2,
                             u16* __restrict__ ws) {
  u16* p0f = ws;                       // fwd W0: K=64,  N=512
  u16* p0b = p0f + D_IN * H_DIM;       // bwd W0^T: K=512, N=64
  u16* p1f = p0b + D_IN * H_DIM;
  u16* p1b = p1f + H_DIM * H_DIM;
  u16* p2f = p1b + H_DIM * H_DIM;
  u16* p2b = p2f + H_DIM * H_DIM;

  int t = blockIdx.x * 256 + threadIdx.x;   // 32768 threads total
  int lane = t & 63;
  int kc   = (t >> 6) & 15;
  int ntg  = t >> 10;                       // 0..31
  int ln = lane & 15, q = lane >> 4;
  int n = ntg * 16 + ln;
  int k = kc * 32 + q * 8;

  #pragma unroll
  for (int j = 0; j < 8; ++j) {
    p1f[t * 8 + j] = f2bf(W1[(k + j) * 512 + n]);
    p2f[t * 8 + j] = f2bf(W2[(k + j) * 512 + n]);
    p1b[t * 8 + j] = f2bf(W1[n * 512 + (k + j)]);
    p2b[t * 8 + j] = f2bf(W2[n * 512 + (k + j)]);
  }
  if (kc < 2) {  // W0 fwd: K=64 -> kc in {0,1}, ntg 0..31
    int t0 = (ntg * 2 + kc) * 64 + lane;
    #pragma unroll
    for (int j = 0; j < 8; ++j)
      p0f[t0 * 8 + j] = f2bf(W0[(k + j) * 512 + n]);   // W0[k][n], k<64
  }
  if (ntg < 4) { // W0 bwd: N=64 -> ntg 0..3, kc 0..15
    int t0 = (ntg * 16 + kc) * 64 + lane;
    #pragma unroll
    for (int j = 0; j < 8; ++j)
      p0b[t0 * 8 + j] = f2bf(W0[n * 512 + (k + j)]);   // W0[n][k], n<64
  }
}

// A-frags for k-chunk KC (4 m-tiles) from LDS.
#define LOAD_A2(DST, KC)                                                        \
  _Pragma("unroll")                                                             \
  for (int mt = 0; mt < 4; ++mt)                                                \
    (DST)[mt] = *(const s16x8*)(buf + (mt * 16 + ln) * AST + (KC) * 32 + q * 8);

// Wave's 4 B-tiles of k-chunk KC straight to VGPRs (contiguous 1KB each).
#define LOAD_B4P(BP, KC, BB)                                                    \
  {                                                                             \
    const u16* _sr = (BP) + ((size_t)wave << 15) + ((KC) << 9) + lane * 8;      \
    _Pragma("unroll")                                                           \
    for (int s = 0; s < 4; ++s)                                                 \
      (BB)[s] = *(const s16x8*)(_sr + (s << 13));                               \
  }
// 4-deep B prologue: chunks 0..3 in flight before the K-loop starts.
#define BB_PROLOGUE(BP)                                                         \
  { LOAD_B4P(BP, 0, bb0); LOAD_B4P(BP, 1, bb1);                                 \
    LOAD_B4P(BP, 2, bb2); LOAD_B4P(BP, 3, bb3); }

// One steady-state step: A prefetched 1 chunk ahead (covers ds latency),
// B refilled 4 chunks ahead (covers L2 latency ~250cyc). PAR = parity const.
#define PIPE_STEP(KC, PAR, BB, BP)                                              \
  {                                                                             \
    LOAD_A2(a[((PAR) + 1) & 1], (KC) + 1);                                      \
    _Pragma("unroll")                                                           \
    for (int nt = 0; nt < 4; ++nt)                                              \
      _Pragma("unroll")                                                         \
      for (int mt = 0; mt < 4; ++mt)                                            \
        acc[mt][nt] = MFMA_BF16(a[(PAR) & 1][mt], (BB)[nt], acc[mt][nt]);       \
    LOAD_B4P(BP, (KC) + 4, BB);                                                 \
  }
// Tail step: no B refill; optional A prefetch.
#define PIPE_TAIL(KC, PAR, BB, LOADA)                                           \
  {                                                                             \
    if (LOADA) LOAD_A2(a[((PAR) + 1) & 1], (KC) + 1);                           \
    _Pragma("unroll")                                                           \
    for (int nt = 0; nt < 4; ++nt)                                              \
      _Pragma("unroll")                                                         \
      for (int mt = 0; mt < 4; ++mt)                                            \
        acc[mt][nt] = MFMA_BF16(a[(PAR) & 1][mt], (BB)[nt], acc[mt][nt]);       \
  }

// 512-wide GEMM K-loop, fully software-pipelined. BB_PROLOGUE(BP) must have
// been issued earlier (during the previous epilogue, pre-barrier).
#define GEMM512_PIPE(BP)                                                        \
  {                                                                             \
    _Pragma("unroll") for (int mt = 0; mt < 4; ++mt)                            \
      _Pragma("unroll") for (int nt = 0; nt < 4; ++nt)                          \
        acc[mt][nt] = (f32x4){0.f, 0.f, 0.f, 0.f};                              \
    s16x8 a[2][4];                                                              \
    LOAD_A2(a[0], 0);                                                           \
    for (int kb = 0; kb < 3; ++kb) {   /* steady state: kc 0..11 */             \
      const int k0 = kb * 4;                                                    \
      PIPE_STEP(k0 + 0, 0, bb0, BP);                                            \
      PIPE_STEP(k0 + 1, 1, bb1, BP);                                            \
      PIPE_STEP(k0 + 2, 2, bb2, BP);                                            \
      PIPE_STEP(k0 + 3, 3, bb3, BP);                                            \
    }                                                                           \
    PIPE_TAIL(12, 0, bb0, 1);          /* kc 12..15: drain */                   \
    PIPE_TAIL(13, 1, bb1, 1);                                                   \
    PIPE_TAIL(14, 0, bb2, 1);                                                   \
    PIPE_TAIL(15, 1, bb3, 0);                                                   \
  }

// block=512 (8 waves), wave = 64x64 slice. Register budget @(512,2)=256/wave:
// acc 64 AGPR + h-packs 64 + bb0-3 64 + a-dbuf 32 + misc ~30 ~= 232 -> fits.
// LDS: single 65KB buf (x tile folded in) -> 2 blocks/CU even at 80KB granule.
__global__ __launch_bounds__(512, 2) void hnn_fused(
    const float* __restrict__ x,
    const float* __restrict__ bias0,
    const float* __restrict__ bias1,
    const float* __restrict__ bias2,
    const float* __restrict__ W3,
    const u16* __restrict__ ws,
    float* __restrict__ out)
{
  const u16* p0f = ws;
  const u16* p0b = p0f + D_IN * H_DIM;
  const u16* p1f = p0b + D_IN * H_DIM;
  const u16* p1b = p1f + H_DIM * H_DIM;
  const u16* p2f = p1b + H_DIM * H_DIM;
  const u16* p2b = p2f + H_DIM * H_DIM;

  __shared__ __align__(16) u16 buf[M_TILE * AST];   // 65 KB; x tile aliases front
  u16* xs = buf;                                    // 64 x XST layout, 9 KB

  const int tid  = threadIdx.x;
  const int wave = tid >> 6;      // 0..7
  const int lane = tid & 63;
  const int ln   = lane & 15;
  const int q    = lane >> 4;
  const int nwb  = wave * 64;     // wave's 64-col slice
  const int row0 = blockIdx.x * M_TILE;

  // ---- stage x tile: 64x64 fp32 -> bf16 into xs (aliases buf) ----
  {
    int r = tid >> 3, c = (tid & 7) * 8;
    const float4* src = (const float4*)(x + (size_t)(row0 + r) * D_IN + c);
    float4 f0 = src[0];
    float4 f1 = src[1];
    u16* dst = xs + r * XST + c;
    dst[0] = f2bf(f0.x); dst[1] = f2bf(f0.y); dst[2] = f2bf(f0.z); dst[3] = f2bf(f0.w);
    dst[4] = f2bf(f1.x); dst[5] = f2bf(f1.y); dst[6] = f2bf(f1.z); dst[7] = f2bf(f1.w);
  }
  __syncthreads();

  f32x4 acc[4][4];
  s16x8 bb0[4], bb1[4], bb2[4], bb3[4];   // 4-deep register-B pipeline
  unsigned h0p[4][4][2];      // h0 bf16x2-packed, C-layout (for tanh' in bwd)
  unsigned h1p[4][4][2];
  float bias[4];

  // ================ GEMM0: z0 = x @ W0  (K=64, inline register-B) ============
  #pragma unroll
  for (int nt = 0; nt < 4; ++nt) bias[nt] = bias0[nwb + nt * 16 + ln];
  #pragma unroll
  for (int mt = 0; mt < 4; ++mt)
    #pragma unroll
    for (int nt = 0; nt < 4; ++nt) acc[mt][nt] = (f32x4){0.f, 0.f, 0.f, 0.f};
  {
    const u16* bpw0 = p0f + (wave << 12) + lane * 8;  // (wave*4 ntg) * 2 kc * 512
    #pragma unroll
    for (int kc = 0; kc < 2; ++kc) {
      s16x8 a0[4];
      #pragma unroll
      for (int mt = 0; mt < 4; ++mt)
        a0[mt] = *(const s16x8*)(xs + (mt * 16 + ln) * XST + kc * 32 + q * 8);
      #pragma unroll
      for (int nt = 0; nt < 4; ++nt) {
        s16x8 b = *(const s16x8*)(bpw0 + (nt << 10) + (kc << 9));
        #pragma unroll
        for (int mt = 0; mt < 4; ++mt)
          acc[mt][nt] = MFMA_BF16(a0[mt], b, acc[mt][nt]);
      }
    }
  }
  __syncthreads();          // all waves done with xs before buf overwrite
  BB_PROLOGUE(p1f);         // GEMM1 chunks 0-3 in flight; overlaps epilogue
  // epilogue: h0 = tanh(z0+b0) -> regs + buf
  #pragma unroll
  for (int mt = 0; mt < 4; ++mt)
    #pragma unroll
    for (int nt = 0; nt < 4; ++nt) {
      int col = nwb + nt * 16 + ln;
      u16 u[4];
      #pragma unroll
      for (int r = 0; r < 4; ++r) {
        float th = fast_tanh(acc[mt][nt][r] + bias[nt]);
        u[r] = f2bf(th);
        buf[(mt * 16 + q * 4 + r) * AST + col] = u[r];
      }
      h0p[mt][nt][0] = (unsigned)u[0] | ((unsigned)u[1] << 16);
      h0p[mt][nt][1] = (unsigned)u[2] | ((unsigned)u[3] << 16);
    }
  __syncthreads();

  // ================ GEMM1: z1 = h0 @ W1 ================
  #pragma unroll
  for (int nt = 0; nt < 4; ++nt) bias[nt] = bias1[nwb + nt * 16 + ln];
  GEMM512_PIPE(p1f);
  __syncthreads();          // all waves done reading h0 (buf)
  BB_PROLOGUE(p2f);         // GEMM2 prefetch
  #pragma unroll
  for (int mt = 0; mt < 4; ++mt)
    #pragma unroll
    for (int nt = 0; nt < 4; ++nt) {
      int col = nwb + nt * 16 + ln;
      u16 u[4];
      #pragma unroll
      for (int r = 0; r < 4; ++r) {
        float th = fast_tanh(acc[mt][nt][r] + bias[nt]);
        u[r] = f2bf(th);
        buf[(mt * 16 + q * 4 + r) * AST + col] = u[r];
      }
      h1p[mt][nt][0] = (unsigned)u[0] | ((unsigned)u[1] << 16);
      h1p[mt][nt][1] = (unsigned)u[2] | ((unsigned)u[3] << 16);
    }
  __syncthreads();

  // ================ GEMM2: z2 = h1 @ W2 ; gz2 = W3*(1-h2^2) ================
  #pragma unroll
  for (int nt = 0; nt < 4; ++nt) bias[nt] = bias2[nwb + nt * 16 + ln];
  float w3v[4];
  #pragma unroll
  for (int nt = 0; nt < 4; ++nt) w3v[nt] = W3[nwb + nt * 16 + ln];
  GEMM512_PIPE(p2f);
  __syncthreads();
  BB_PROLOGUE(p2b);         // GEMM3 prefetch
  #pragma unroll
  for (int mt = 0; mt < 4; ++mt)
    #pragma unroll
    for (int nt = 0; nt < 4; ++nt) {
      int col = nwb + nt * 16 + ln;
      #pragma unroll
      for (int r = 0; r < 4; ++r) {
        float th = fast_tanh(acc[mt][nt][r] + bias[nt]);
        float gz = w3v[nt] * (1.0f - th * th);
        buf[(mt * 16 + q * 4 + r) * AST + col] = f2bf(gz);
      }
    }
  __syncthreads();

  // ================ GEMM3: g1 = gz2 @ W2^T ; gz1 = g1*(1-h1^2) ================
  GEMM512_PIPE(p2b);
  __syncthreads();
  BB_PROLOGUE(p1b);         // GEMM4 prefetch
  #pragma unroll
  for (int mt = 0; mt < 4; ++mt)
    #pragma unroll
    for (int nt = 0; nt < 4; ++nt) {
      int col = nwb + nt * 16 + ln;
      unsigned pa = h1p[mt][nt][0], pb = h1p[mt][nt][1];
      float hh[4] = { bfb2f(pa & 0xffffu), bfb2f(pa >> 16),
                      bfb2f(pb & 0xffffu), bfb2f(pb >> 16) };
      #pragma unroll
      for (int r = 0; r < 4; ++r) {
        float gz = acc[mt][nt][r] * (1.0f - hh[r] * hh[r]);
        buf[(mt * 16 + q * 4 + r) * AST + col] = f2bf(gz);
      }
    }
  __syncthreads();

  // ================ GEMM4: g0 = gz1 @ W1^T ; gz0 = g0*(1-h0^2) ================
  GEMM512_PIPE(p1b);
  __syncthreads();
  #pragma unroll
  for (int mt = 0; mt < 4; ++mt)
    #pragma unroll
    for (int nt = 0; nt < 4; ++nt) {
      int col = nwb + nt * 16 + ln;
      unsigned pa = h0p[mt][nt][0], pb = h0p[mt][nt][1];
      float hh[4] = { bfb2f(pa & 0xffffu), bfb2f(pa >> 16),
                      bfb2f(pb & 0xffffu), bfb2f(pb >> 16) };
      #pragma unroll
      for (int r = 0; r < 4; ++r) {
        float gz = acc[mt][nt][r] * (1.0f - hh[r] * hh[r]);
        buf[(mt * 16 + q * 4 + r) * AST + col] = f2bf(gz);
      }
    }
  __syncthreads();

  // ================ GEMM5: gradH = gz0 @ W0^T (64x64), symplectic store ======
  // 8 waves x two 16x16 tiles: row tile = wave&3, col half = wave>>2.
  {
    f32x4 acc5[2];
    acc5[0] = (f32x4){0.f, 0.f, 0.f, 0.f};
    acc5[1] = (f32x4){0.f, 0.f, 0.f, 0.f};
    const int mt5 = wave & 3;                  // row tile 0..3
    const int nb5 = (wave >> 2) * 32;          // gradH column base (0 or 32)
    const u16* bp5 = p0b + ((wave >> 2) << 14) + lane * 8;  // ntg5*16kc*512
    #pragma unroll 2
    for (int kc = 0; kc < 16; ++kc) {
      s16x8 a5 = *(const s16x8*)(buf + (mt5 * 16 + ln) * AST + kc * 32 + q * 8);
      #pragma unroll
      for (int nt = 0; nt < 2; ++nt) {
        s16x8 b = *(const s16x8*)(bp5 + (nt << 13) + (kc << 9));
        acc5[nt] = MFMA_BF16(a5, b, acc5[nt]);
      }
    }
    #pragma unroll
    for (int nt = 0; nt < 2; ++nt) {
      int g = nb5 + nt * 16 + ln;                 // gradH column
      int c = (g < 32) ? g + 32 : g - 32;         // out = concat(gradH[:,32:], -gradH[:,:32])
      float s = (g < 32) ? -1.0f : 1.0f;
      #pragma unroll
      for (int r = 0; r < 4; ++r) {
        int grow = row0 + mt5 * 16 + q * 4 + r;
        out[(size_t)grow * 64 + c] = s * acc5[nt][r];
      }
    }
  }
}

extern "C" void kernel_launch(void* const* d_in, const int* in_sizes, int n_in,
                              void* d_out, int out_size, void* d_ws, size_t ws_size,
                              hipStream_t stream) {
  // setup_inputs order: t, x, W0, b0, W1, b1, W2, b2, W3, b3
  const float* x  = (const float*)d_in[1];
  const float* W0 = (const float*)d_in[2];
  const float* b0 = (const float*)d_in[3];
  const float* W1 = (const float*)d_in[4];
  const float* b1 = (const float*)d_in[5];
  const float* W2 = (const float*)d_in[6];
  const float* b2 = (const float*)d_in[7];
  const float* W3 = (const float*)d_in[8];
  u16* ws = (u16*)d_ws;
  float* out = (float*)d_out;

  prep_weights<<<128, 256, 0, stream>>>(W0, W1, W2, ws);
  hnn_fused<<<65536 / M_TILE, 512, 0, stream>>>(x, b0, b1, b2, W3, ws, out);
}

// Round 12
// 228.566 us; speedup vs baseline: 1.6793x; 1.6793x over previous
//
#include <hip/hip_runtime.h>
#include <hip/hip_bf16.h>

typedef unsigned short u16;
typedef short s16x8 __attribute__((ext_vector_type(8)));
typedef float f32x4 __attribute__((ext_vector_type(4)));

#define MFMA_BF16(a, b, c) __builtin_amdgcn_mfma_f32_16x16x32_bf16((a), (b), (c), 0, 0, 0)

static constexpr int D_IN   = 64;
static constexpr int H_DIM  = 512;
static constexpr int M_TILE = 64;
static constexpr int AST    = 520;  // LDS row stride (bf16)
static constexpr int XST    = 72;   // LDS row stride for x tile

__device__ __forceinline__ u16 f2bf(float f) {
  unsigned u = __builtin_bit_cast(unsigned, f);
  u += 0x7fffu + ((u >> 16) & 1u);   // RNE
  return (u16)(u >> 16);
}
__device__ __forceinline__ float bfb2f(unsigned bits16) {
  return __builtin_bit_cast(float, bits16 << 16);
}
__device__ __forceinline__ float fast_tanh(float x) {
  float e = __expf(2.0f * x);
  return 1.0f - 2.0f * __builtin_amdgcn_rcpf(e + 1.0f);
}

// ---- prep: fp32 weights -> bf16, packed in MFMA-B-fragment order ----
// For each (ntg = 16-col tile, kc = 32-wide K chunk): 512 elems stored as
// lane*8 contiguous, lane=(q*16+ln), elem j -> B[k=kc*32+q*8+j][n=ntg*16+ln].
// ws layout (bf16): p0f[64x512] p0b[512x64] p1f p1b p2f p2b  (~2.2MB)
__global__ void prep_weights(const float* __restrict__ W0,
                             const float* __restrict__ W1,
                             const float* __restrict__ W2,
                             u16* __restrict__ ws) {
  u16* p0f = ws;                       // fwd W0: K=64,  N=512
  u16* p0b = p0f + D_IN * H_DIM;       // bwd W0^T: K=512, N=64
  u16* p1f = p0b + D_IN * H_DIM;
  u16* p1b = p1f + H_DIM * H_DIM;
  u16* p2f = p1b + H_DIM * H_DIM;
  u16* p2b = p2f + H_DIM * H_DIM;

  int t = blockIdx.x * 256 + threadIdx.x;   // 32768 threads total
  int lane = t & 63;
  int kc   = (t >> 6) & 15;
  int ntg  = t >> 10;                       // 0..31
  int ln = lane & 15, q = lane >> 4;
  int n = ntg * 16 + ln;
  int k = kc * 32 + q * 8;

  #pragma unroll
  for (int j = 0; j < 8; ++j) {
    p1f[t * 8 + j] = f2bf(W1[(k + j) * 512 + n]);
    p2f[t * 8 + j] = f2bf(W2[(k + j) * 512 + n]);
    p1b[t * 8 + j] = f2bf(W1[n * 512 + (k + j)]);
    p2b[t * 8 + j] = f2bf(W2[n * 512 + (k + j)]);
  }
  if (kc < 2) {  // W0 fwd: K=64 -> kc in {0,1}, ntg 0..31
    int t0 = (ntg * 2 + kc) * 64 + lane;
    #pragma unroll
    for (int j = 0; j < 8; ++j)
      p0f[t0 * 8 + j] = f2bf(W0[(k + j) * 512 + n]);   // W0[k][n], k<64
  }
  if (ntg < 4) { // W0 bwd: N=64 -> ntg 0..3, kc 0..15
    int t0 = (ntg * 16 + kc) * 64 + lane;
    #pragma unroll
    for (int j = 0; j < 8; ++j)
      p0b[t0 * 8 + j] = f2bf(W0[n * 512 + (k + j)]);   // W0[n][k], n<64
  }
}

// Load this wave's 4 B-tiles of k-chunk KC straight into VGPRs (BB[4]).
// Each load = contiguous 1KB per wave (frag-packed). No LDS round-trip.
#define LOAD_B4(BP, KC, BB)                                                     \
  {                                                                             \
    const u16* _sr = (BP) + ((size_t)wave << 15) + ((KC) << 9) + lane * 8;      \
    _Pragma("unroll")                                                           \
    for (int s = 0; s < 4; ++s)                                                 \
      (BB)[s] = *(const s16x8*)(_sr + (s << 13));                               \
  }
// 3-deep prologue: chunks 0,1,2 in flight before the K-loop.
#define BB_PROLOGUE3(BP)                                                        \
  { LOAD_B4(BP, 0, bb0); LOAD_B4(BP, 1, bb1); LOAD_B4(BP, 2, bb2); }

// One K-step: A-frags (4 m-tiles) from LDS, 16 MFMAs on buffer BB, then
// refill BB with chunk KC+3 (prefetch distance 2 kc ~= 160-260cyc of MFMA).
#define STEP3(KC, BB, BP)                                                       \
  {                                                                             \
    s16x8 a[4];                                                                 \
    _Pragma("unroll")                                                           \
    for (int mt = 0; mt < 4; ++mt)                                              \
      a[mt] = *(const s16x8*)(buf + (mt * 16 + ln) * AST + (KC) * 32 + q * 8);  \
    _Pragma("unroll")                                                           \
    for (int nt = 0; nt < 4; ++nt)                                              \
      _Pragma("unroll")                                                         \
      for (int mt = 0; mt < 4; ++mt)                                            \
        acc[mt][nt] = MFMA_BF16(a[mt], (BB)[nt], acc[mt][nt]);                  \
    if ((KC) + 3 < 16) LOAD_B4(BP, (KC) + 3, BB);                               \
  }

// 512-wide GEMM K-loop: wave = 64 rows x 64 cols (4 m x 4 n tiles).
// B all-register, 3-buffer rotation (kc%3). BB_PROLOGUE3(BP) must have been
// issued during the preceding epilogue (pre-barrier) to overlap with VALU.
#define GEMM512_REG(BP)                                                         \
  {                                                                             \
    _Pragma("unroll") for (int mt = 0; mt < 4; ++mt)                            \
      _Pragma("unroll") for (int nt = 0; nt < 4; ++nt)                          \
        acc[mt][nt] = (f32x4){0.f, 0.f, 0.f, 0.f};                              \
    STEP3( 0, bb0, BP); STEP3( 1, bb1, BP); STEP3( 2, bb2, BP);                 \
    STEP3( 3, bb0, BP); STEP3( 4, bb1, BP); STEP3( 5, bb2, BP);                 \
    STEP3( 6, bb0, BP); STEP3( 7, bb1, BP); STEP3( 8, bb2, BP);                 \
    STEP3( 9, bb0, BP); STEP3(10, bb1, BP); STEP3(11, bb2, BP);                 \
    STEP3(12, bb0, BP); STEP3(13, bb1, BP); STEP3(14, bb2, BP);                 \
    STEP3(15, bb0, BP);                                                         \
  }

// block=512 (8 waves), wave = 64x64 slice. Register budget @(512,2)=256/wave:
// acc 64 AGPR + h-packs 64 + bb0-2 48 + a-temp 32 + misc ~30 ~= 216 -> fits.
// (round-11 lesson: +64 regs spilled; +16 is the affordable increment.)
// Occupancy is register-pool-capped at 8 waves/CU regardless of LDS.
__global__ __launch_bounds__(512, 2) void hnn_fused(
    const float* __restrict__ x,
    const float* __restrict__ bias0,
    const float* __restrict__ bias1,
    const float* __restrict__ bias2,
    const float* __restrict__ W3,
    const u16* __restrict__ ws,
    float* __restrict__ out)
{
  const u16* p0f = ws;
  const u16* p0b = p0f + D_IN * H_DIM;
  const u16* p1f = p0b + D_IN * H_DIM;
  const u16* p1b = p1f + H_DIM * H_DIM;
  const u16* p2f = p1b + H_DIM * H_DIM;
  const u16* p2b = p2f + H_DIM * H_DIM;

  __shared__ __align__(16) u16 xs[M_TILE * XST];    // 9.0 KB
  __shared__ __align__(16) u16 buf[M_TILE * AST];   // 65.0 KB (A activations)

  const int tid  = threadIdx.x;
  const int wave = tid >> 6;      // 0..7
  const int lane = tid & 63;
  const int ln   = lane & 15;
  const int q    = lane >> 4;
  const int nwb  = wave * 64;     // wave's 64-col slice
  const int row0 = blockIdx.x * M_TILE;

  // ---- stage x tile: 64x64 fp32 -> bf16 LDS (512 thr x 8 elems) ----
  {
    int r = tid >> 3, c = (tid & 7) * 8;
    const float4* src = (const float4*)(x + (size_t)(row0 + r) * D_IN + c);
    float4 f0 = src[0];
    float4 f1 = src[1];
    u16* dst = xs + r * XST + c;
    dst[0] = f2bf(f0.x); dst[1] = f2bf(f0.y); dst[2] = f2bf(f0.z); dst[3] = f2bf(f0.w);
    dst[4] = f2bf(f1.x); dst[5] = f2bf(f1.y); dst[6] = f2bf(f1.z); dst[7] = f2bf(f1.w);
  }
  __syncthreads();

  f32x4 acc[4][4];
  s16x8 bb0[4], bb1[4], bb2[4];   // 3-deep register-B rotation
  unsigned h0p[4][4][2];      // h0 bf16x2-packed, C-layout (for tanh' in bwd)
  unsigned h1p[4][4][2];
  float bias[4];

  // ================ GEMM0: z0 = x @ W0  (K=64, inline register-B) ============
  #pragma unroll
  for (int nt = 0; nt < 4; ++nt) bias[nt] = bias0[nwb + nt * 16 + ln];
  #pragma unroll
  for (int mt = 0; mt < 4; ++mt)
    #pragma unroll
    for (int nt = 0; nt < 4; ++nt) acc[mt][nt] = (f32x4){0.f, 0.f, 0.f, 0.f};
  {
    const u16* bpw0 = p0f + (wave << 12) + lane * 8;  // (wave*4 ntg) * 2 kc * 512
    #pragma unroll
    for (int kc = 0; kc < 2; ++kc) {
      s16x8 a0[4];
      #pragma unroll
      for (int mt = 0; mt < 4; ++mt)
        a0[mt] = *(const s16x8*)(xs + (mt * 16 + ln) * XST + kc * 32 + q * 8);
      #pragma unroll
      for (int nt = 0; nt < 4; ++nt) {
        s16x8 b = *(const s16x8*)(bpw0 + (nt << 10) + (kc << 9));
        #pragma unroll
        for (int mt = 0; mt < 4; ++mt)
          acc[mt][nt] = MFMA_BF16(a0[mt], b, acc[mt][nt]);
      }
    }
  }
  BB_PROLOGUE3(p1f);   // prefetch GEMM1 kc 0-2; overlaps epilogue VALU
  // epilogue: h0 = tanh(z0+b0) -> regs + buf (buf first use, no barrier needed)
  #pragma unroll
  for (int mt = 0; mt < 4; ++mt)
    #pragma unroll
    for (int nt = 0; nt < 4; ++nt) {
      int col = nwb + nt * 16 + ln;
      u16 u[4];
      #pragma unroll
      for (int r = 0; r < 4; ++r) {
        float th = fast_tanh(acc[mt][nt][r] + bias[nt]);
        u[r] = f2bf(th);
        buf[(mt * 16 + q * 4 + r) * AST + col] = u[r];
      }
      h0p[mt][nt][0] = (unsigned)u[0] | ((unsigned)u[1] << 16);
      h0p[mt][nt][1] = (unsigned)u[2] | ((unsigned)u[3] << 16);
    }
  __syncthreads();

  // ================ GEMM1: z1 = h0 @ W1 ================
  #pragma unroll
  for (int nt = 0; nt < 4; ++nt) bias[nt] = bias1[nwb + nt * 16 + ln];
  GEMM512_REG(p1f);
  __syncthreads();          // all waves done reading h0 (buf)
  BB_PROLOGUE3(p2f);        // prefetch GEMM2
  #pragma unroll
  for (int mt = 0; mt < 4; ++mt)
    #pragma unroll
    for (int nt = 0; nt < 4; ++nt) {
      int col = nwb + nt * 16 + ln;
      u16 u[4];
      #pragma unroll
      for (int r = 0; r < 4; ++r) {
        float th = fast_tanh(acc[mt][nt][r] + bias[nt]);
        u[r] = f2bf(th);
        buf[(mt * 16 + q * 4 + r) * AST + col] = u[r];
      }
      h1p[mt][nt][0] = (unsigned)u[0] | ((unsigned)u[1] << 16);
      h1p[mt][nt][1] = (unsigned)u[2] | ((unsigned)u[3] << 16);
    }
  __syncthreads();

  // ================ GEMM2: z2 = h1 @ W2 ; gz2 = W3*(1-h2^2) ================
  #pragma unroll
  for (int nt = 0; nt < 4; ++nt) bias[nt] = bias2[nwb + nt * 16 + ln];
  float w3v[4];
  #pragma unroll
  for (int nt = 0; nt < 4; ++nt) w3v[nt] = W3[nwb + nt * 16 + ln];
  GEMM512_REG(p2f);
  __syncthreads();
  BB_PROLOGUE3(p2b);        // prefetch GEMM3
  #pragma unroll
  for (int mt = 0; mt < 4; ++mt)
    #pragma unroll
    for (int nt = 0; nt < 4; ++nt) {
      int col = nwb + nt * 16 + ln;
      #pragma unroll
      for (int r = 0; r < 4; ++r) {
        float th = fast_tanh(acc[mt][nt][r] + bias[nt]);
        float gz = w3v[nt] * (1.0f - th * th);
        buf[(mt * 16 + q * 4 + r) * AST + col] = f2bf(gz);
      }
    }
  __syncthreads();

  // ================ GEMM3: g1 = gz2 @ W2^T ; gz1 = g1*(1-h1^2) ================
  GEMM512_REG(p2b);
  __syncthreads();
  BB_PROLOGUE3(p1b);        // prefetch GEMM4
  #pragma unroll
  for (int mt = 0; mt < 4; ++mt)
    #pragma unroll
    for (int nt = 0; nt < 4; ++nt) {
      int col = nwb + nt * 16 + ln;
      unsigned pa = h1p[mt][nt][0], pb = h1p[mt][nt][1];
      float hh[4] = { bfb2f(pa & 0xffffu), bfb2f(pa >> 16),
                      bfb2f(pb & 0xffffu), bfb2f(pb >> 16) };
      #pragma unroll
      for (int r = 0; r < 4; ++r) {
        float gz = acc[mt][nt][r] * (1.0f - hh[r] * hh[r]);
        buf[(mt * 16 + q * 4 + r) * AST + col] = f2bf(gz);
      }
    }
  __syncthreads();

  // ================ GEMM4: g0 = gz1 @ W1^T ; gz0 = g0*(1-h0^2) ================
  GEMM512_REG(p1b);
  __syncthreads();
  #pragma unroll
  for (int mt = 0; mt < 4; ++mt)
    #pragma unroll
    for (int nt = 0; nt < 4; ++nt) {
      int col = nwb + nt * 16 + ln;
      unsigned pa = h0p[mt][nt][0], pb = h0p[mt][nt][1];
      float hh[4] = { bfb2f(pa & 0xffffu), bfb2f(pa >> 16),
                      bfb2f(pb & 0xffffu), bfb2f(pb >> 16) };
      #pragma unroll
      for (int r = 0; r < 4; ++r) {
        float gz = acc[mt][nt][r] * (1.0f - hh[r] * hh[r]);
        buf[(mt * 16 + q * 4 + r) * AST + col] = f2bf(gz);
      }
    }
  __syncthreads();

  // ================ GEMM5: gradH = gz0 @ W0^T (64x64), symplectic store ======
  // 8 waves x two 16x16 tiles: row tile = wave&3, col half = wave>>2.
  {
    f32x4 acc5[2];
    acc5[0] = (f32x4){0.f, 0.f, 0.f, 0.f};
    acc5[1] = (f32x4){0.f, 0.f, 0.f, 0.f};
    const int mt5 = wave & 3;                  // row tile 0..3
    const int nb5 = (wave >> 2) * 32;          // gradH column base (0 or 32)
    const u16* bp5 = p0b + ((wave >> 2) << 14) + lane * 8;  // ntg5*16kc*512
    #pragma unroll 2
    for (int kc = 0; kc < 16; ++kc) {
      s16x8 a5 = *(const s16x8*)(buf + (mt5 * 16 + ln) * AST + kc * 32 + q * 8);
      #pragma unroll
      for (int nt = 0; nt < 2; ++nt) {
        s16x8 b = *(const s16x8*)(bp5 + (nt << 13) + (kc << 9));
        acc5[nt] = MFMA_BF16(a5, b, acc5[nt]);
      }
    }
    #pragma unroll
    for (int nt = 0; nt < 2; ++nt) {
      int g = nb5 + nt * 16 + ln;                 // gradH column
      int c = (g < 32) ? g + 32 : g - 32;         // out = concat(gradH[:,32:], -gradH[:,:32])
      float s = (g < 32) ? -1.0f : 1.0f;
      #pragma unroll
      for (int r = 0; r < 4; ++r) {
        int grow = row0 + mt5 * 16 + q * 4 + r;
        out[(size_t)grow * 64 + c] = s * acc5[nt][r];
      }
    }
  }
}

extern "C" void kernel_launch(void* const* d_in, const int* in_sizes, int n_in,
                              void* d_out, int out_size, void* d_ws, size_t ws_size,
                              hipStream_t stream) {
  // setup_inputs order: t, x, W0, b0, W1, b1, W2, b2, W3, b3
  const float* x  = (const float*)d_in[1];
  const float* W0 = (const float*)d_in[2];
  const float* b0 = (const float*)d_in[3];
  const float* W1 = (const float*)d_in[4];
  const float* b1 = (const float*)d_in[5];
  const float* W2 = (const float*)d_in[6];
  const float* b2 = (const float*)d_in[7];
  const float* W3 = (const float*)d_in[8];
  u16* ws = (u16*)d_ws;
  float* out = (float*)d_out;

  prep_weights<<<128, 256, 0, stream>>>(W0, W1, W2, ws);
  hnn_fused<<<65536 / M_TILE, 512, 0, stream>>>(x, b0, b1, b2, W3, ws, out);
}